// Round 4
// baseline (613.764 us; speedup 1.0000x reference)
//
#include <hip/hip_runtime.h>
#include <hip/hip_cooperative_groups.h>

namespace cg = cooperative_groups;

#define BATCH 8
#define PN    16384
#define NSAMP 256
#define KDIM  512
#define HID   384
#define HALF  192
#define CIN   576   // HID + HALF
#define ROWS  2048  // BATCH * NSAMP
#define BN_EPS 1e-5f

// workspace offsets (in floats)
#define OFF_GF   0
#define OFF_W1T  3072
#define OFF_W2T  224256
#define OFF_IDX  371712   /* 2048 ints */
#define OFF_H1   373760
#define OFF_H2   1160192
#define OFF_SUM1 1946624
#define OFF_SQ1  1947008
#define OFF_SUM2 1947392
#define OFF_SQ2  1947776

// One cooperative kernel: phase A (FPS blocks 0-7 + prep blocks 8-32),
// grid.sync, gemm1, grid.sync, gemm2, grid.sync, out.
// FPS math is bit-identical to the passing R2/R3 kernels (same per-point fp32
// ops, same packed-key tiebreak) -> identical sample indices.
__global__ __launch_bounds__(512, 2) void k_all(
    const float* __restrict__ p,  const float* __restrict__ Wc,
    const float* __restrict__ bc, const float* __restrict__ pf,
    const float* __restrict__ Wf, const float* __restrict__ bfe,
    const float* __restrict__ W1, const float* __restrict__ b1,
    const float* __restrict__ g1, const float* __restrict__ be1,
    const float* __restrict__ W2, const float* __restrict__ b2,
    const float* __restrict__ g2, const float* __restrict__ be2,
    float* __restrict__ ws, float* __restrict__ out) {
  cg::grid_group grid = cg::this_grid();
  int blk = blockIdx.x, t = threadIdx.x;

  __shared__ float s[KDIM];
  __shared__ float Msh[6];
  __shared__ unsigned long long red[2][8];
  __shared__ __align__(16) float ct[CIN * 8];   // phase B staging
  __shared__ __align__(16) float ht[HID * 8];   // phase C staging
  __shared__ float sA[HID], sB[HID];            // BN scale/shift (C, then D)

  int* idx_out = (int*)(ws + OFF_IDX);

  // ======================= Phase A =======================
  if (blk < 8) {
    // ---- FPS, one batch per block (Mahalanobis rank-3 trick) ----
    int b = blk;
    if (t < 64) {                      // G = Wc Wc^T (fp64) + Cholesky, wave 0
      double g0 = 0, g1d = 0, g2d = 0, g3 = 0, g4 = 0, g5 = 0;
      for (int k = t; k < HALF; k += 64) {
        double w0 = (double)Wc[k];
        double w1 = (double)Wc[HALF + k];
        double w2 = (double)Wc[2 * HALF + k];
        g0 += w0 * w0; g1d += w0 * w1; g2d += w0 * w2;
        g3 += w1 * w1; g4  += w1 * w2; g5  += w2 * w2;
      }
      for (int off = 32; off; off >>= 1) {
        g0 += __shfl_down(g0, off, 64); g1d += __shfl_down(g1d, off, 64);
        g2d += __shfl_down(g2d, off, 64); g3 += __shfl_down(g3, off, 64);
        g4 += __shfl_down(g4, off, 64); g5 += __shfl_down(g5, off, 64);
      }
      if (t == 0) {
        double l00 = sqrt(g0);
        double l10 = g1d / l00, l20 = g2d / l00;
        double l11 = sqrt(g3 - l10 * l10);
        double l21 = (g4 - l10 * l20) / l11;
        double l22 = sqrt(g5 - l20 * l20 - l21 * l21);
        Msh[0] = (float)l00; Msh[1] = (float)l10; Msh[2] = (float)l20;
        Msh[3] = (float)l11; Msh[4] = (float)l21; Msh[5] = (float)l22;
      }
    }
    __syncthreads();
    float m00 = Msh[0], m10 = Msh[1], m20 = Msh[2];
    float m11 = Msh[3], m21 = Msh[4], m22 = Msh[5];

    const float* pb = p + b * PN * 3;
    float qx[32], qy[32], qz[32], dist[32];
#pragma unroll
    for (int j = 0; j < 32; j++) {
      int i = (j << 9) + t;            // strided ownership: i = j*512 + t
      float x = pb[i * 3], y = pb[i * 3 + 1], z = pb[i * 3 + 2];
      qx[j] = fmaf(m00, x, fmaf(m10, y, m20 * z));
      qy[j] = fmaf(m11, y, m21 * z);
      qz[j] = m22 * z;
      dist[j] = 1e10f;
    }

    int far = 0, par = 0;
    for (int k = 0; k < NSAMP; k++) {
      if (t == 0) idx_out[b * NSAMP + k] = far;  // scan emits pre-update far
      float x = pb[far * 3], y = pb[far * 3 + 1], z = pb[far * 3 + 2];
      float cx = fmaf(m00, x, fmaf(m10, y, m20 * z));
      float cy = fmaf(m11, y, m21 * z);
      float cz = m22 * z;
      float bv = -1.f; unsigned bj = 0;
#pragma unroll
      for (int j = 0; j < 32; j++) {
        float dx = qx[j] - cx, dy = qy[j] - cy, dz = qz[j] - cz;
        float d  = fmaf(dx, dx, fmaf(dy, dy, dz * dz));
        float nd = fminf(dist[j], d);
        dist[j] = nd;
        bool gt = nd > bv;                       // strict > : first-index tiebreak
        bv = gt ? nd : bv;
        bj = gt ? (unsigned)j : bj;
      }
      unsigned bi = (bj << 9) + (unsigned)t;
      // pack: larger dist wins; equal dist -> smaller global index wins (~bi)
      unsigned long long key =
          (((unsigned long long)__float_as_uint(bv)) << 32) | (unsigned)(~bi);
#pragma unroll
      for (int off = 32; off; off >>= 1) {       // per-wave butterfly
        unsigned long long o = __shfl_xor(key, off, 64);
        key = (o > key) ? o : key;
      }
      if ((t & 63) == 0) red[par][t >> 6] = key;
      __syncthreads();                           // the ONLY barrier per step
      // all lanes: read one of 8 slots, 3-level butterfly -> global max
      unsigned long long k2 = red[par][t & 7];
#pragma unroll
      for (int off = 1; off < 8; off <<= 1) {    // (L^off)&7 == (L&7)^off
        unsigned long long o = __shfl_xor(k2, off, 64);
        k2 = (o > k2) ? o : k2;
      }
      far = __builtin_amdgcn_readfirstlane((int)(~((unsigned)k2)));
      par ^= 1;                                  // double-buffer: no 2nd barrier
    }
  } else if (blk < 16) {               // W1t[c][o] = W1[o][c]
    for (int sI = (blk - 8) * 512 + t; sI < HID * CIN; sI += 4096) {
      int o = sI / CIN, c = sI % CIN;
      ws[OFF_W1T + c * HID + o] = W1[sI];
    }
  } else if (blk < 24) {               // W2t[c][o] = W2[o][c]
    for (int sI = (blk - 16) * 512 + t; sI < HID * HID; sI += 4096) {
      int o = sI / HID, c = sI % HID;
      ws[OFF_W2T + c * HID + o] = W2[sI];
    }
  } else if (blk < 32) {               // global_feat[b] = pf[b] @ W_feat + b_feat
    int b = blk - 24;
    s[t] = pf[b * KDIM + t];           // KDIM == 512 == blockDim
    __syncthreads();
    if (t < HID) {
      float acc = bfe[t];
      for (int k = 0; k < KDIM; k++) acc = fmaf(s[k], Wf[k * HID + t], acc);
      ws[OFF_GF + b * HID + t] = acc;
    }
  } else if (blk == 32) {              // zero BN sums (contiguous 1536 floats)
    for (int i = t; i < 1536; i += 512) ws[OFF_SUM1 + i] = 0.f;
  }
  grid.sync();

  // ======================= Phase B: GEMM1 + BN1 sums =======================
  {
    int row0 = blk * 8;
    const int* fidx = (const int*)(ws + OFF_IDX);
    for (int sI = t; sI < 8 * CIN; sI += 512) { // stage tile transposed ct[c*8+r]
      int r = sI / CIN, c = sI % CIN;
      int row = row0 + r, b = row >> 8;
      float val;
      if (c < HID) {
        val = ws[OFF_GF + b * HID + c];          // broadcast global_feat
      } else {
        int co = c - HID;
        int i = fidx[row];
        const float* pp = p + (b * PN + i) * 3;
        val = bc[co];
        val = fmaf(pp[0], Wc[co], val);
        val = fmaf(pp[1], Wc[HALF + co], val);
        val = fmaf(pp[2], Wc[2 * HALF + co], val);  // sampled local_feat
      }
      ct[c * 8 + r] = val;
    }
    __syncthreads();
    if (t < HID) {
      const float* w1t = ws + OFF_W1T;
      float acc[8] = {0.f, 0.f, 0.f, 0.f, 0.f, 0.f, 0.f, 0.f};
      for (int c = 0; c < CIN; c++) {
        float w = w1t[c * HID + t];
        float4 a0 = *(const float4*)(ct + c * 8);
        float4 a1 = *(const float4*)(ct + c * 8 + 4);
        acc[0] = fmaf(a0.x, w, acc[0]); acc[1] = fmaf(a0.y, w, acc[1]);
        acc[2] = fmaf(a0.z, w, acc[2]); acc[3] = fmaf(a0.w, w, acc[3]);
        acc[4] = fmaf(a1.x, w, acc[4]); acc[5] = fmaf(a1.y, w, acc[5]);
        acc[6] = fmaf(a1.z, w, acc[6]); acc[7] = fmaf(a1.w, w, acc[7]);
      }
      float bias = b1[t];
      float sv = 0.f, sq = 0.f;
#pragma unroll
      for (int r = 0; r < 8; r++) {
        float v = acc[r] + bias;
        ws[OFF_H1 + (row0 + r) * HID + t] = v;
        sv += v; sq = fmaf(v, v, sq);
      }
      atomicAdd(&ws[OFF_SUM1 + t], sv);
      atomicAdd(&ws[OFF_SQ1 + t], sq);
    }
  }
  grid.sync();

  // ============== Phase C: GEMM2, BN1 finalize + ReLU fused on load =========
  {
    int row0 = blk * 8;
    if (t < HID) {                     // BN1 finalize, redundantly per block
      float m = ws[OFF_SUM1 + t] * (1.f / ROWS);
      float v = ws[OFF_SQ1 + t] * (1.f / ROWS) - m * m;
      float sc = (1.f / sqrtf(v + BN_EPS)) * g1[t];
      sA[t] = sc;
      sB[t] = be1[t] - m * sc;
    }
    __syncthreads();
    for (int sI = t; sI < 8 * HID; sI += 512) {
      int r = sI / HID, c = sI % HID;
      float x = fmaf(ws[OFF_H1 + (row0 + r) * HID + c], sA[c], sB[c]);
      ht[c * 8 + r] = fmaxf(x, 0.f);
    }
    __syncthreads();
    if (t < HID) {
      const float* w2t = ws + OFF_W2T;
      float acc[8] = {0.f, 0.f, 0.f, 0.f, 0.f, 0.f, 0.f, 0.f};
      for (int c = 0; c < HID; c++) {
        float w = w2t[c * HID + t];
        float4 a0 = *(const float4*)(ht + c * 8);
        float4 a1 = *(const float4*)(ht + c * 8 + 4);
        acc[0] = fmaf(a0.x, w, acc[0]); acc[1] = fmaf(a0.y, w, acc[1]);
        acc[2] = fmaf(a0.z, w, acc[2]); acc[3] = fmaf(a0.w, w, acc[3]);
        acc[4] = fmaf(a1.x, w, acc[4]); acc[5] = fmaf(a1.y, w, acc[5]);
        acc[6] = fmaf(a1.z, w, acc[6]); acc[7] = fmaf(a1.w, w, acc[7]);
      }
      float bias = b2[t];
      float sv = 0.f, sq = 0.f;
#pragma unroll
      for (int r = 0; r < 8; r++) {
        float v = acc[r] + bias;
        ws[OFF_H2 + (row0 + r) * HID + t] = v;
        sv += v; sq = fmaf(v, v, sq);
      }
      atomicAdd(&ws[OFF_SUM2 + t], sv);
      atomicAdd(&ws[OFF_SQ2 + t], sq);
    }
  }
  grid.sync();

  // ============== Phase D: BN2 finalize + affine + ReLU ====================
  {
    if (t < HID) {
      float m = ws[OFF_SUM2 + t] * (1.f / ROWS);
      float v = ws[OFF_SQ2 + t] * (1.f / ROWS) - m * m;
      float sc = (1.f / sqrtf(v + BN_EPS)) * g2[t];
      sA[t] = sc;
      sB[t] = be2[t] - m * sc;
    }
    __syncthreads();
    for (int i4 = blk * 512 + t; i4 < ROWS * HID / 4; i4 += 256 * 512) {
      int i = i4 * 4;
      int c = i % HID;                 // multiple of 4
      float4 h = *(const float4*)(ws + OFF_H2 + i);
      float4 r;
      r.x = fmaxf(fmaf(h.x, sA[c],     sB[c]),     0.f);
      r.y = fmaxf(fmaf(h.y, sA[c + 1], sB[c + 1]), 0.f);
      r.z = fmaxf(fmaf(h.z, sA[c + 2], sB[c + 2]), 0.f);
      r.w = fmaxf(fmaf(h.w, sA[c + 3], sB[c + 3]), 0.f);
      ((float4*)out)[i4] = r;
    }
  }
}

extern "C" void kernel_launch(void* const* d_in, const int* in_sizes, int n_in,
                              void* d_out, int out_size, void* d_ws, size_t ws_size,
                              hipStream_t stream) {
  const float* p   = (const float*)d_in[0];
  // d_in[1] = N (int scalar, always 256)
  const float* pf  = (const float*)d_in[2];
  const float* Wf  = (const float*)d_in[3];
  const float* bfe = (const float*)d_in[4];
  const float* Wc  = (const float*)d_in[5];
  const float* bc  = (const float*)d_in[6];
  const float* W1  = (const float*)d_in[7];
  const float* b1  = (const float*)d_in[8];
  const float* g1  = (const float*)d_in[9];
  const float* be1 = (const float*)d_in[10];
  const float* W2  = (const float*)d_in[11];
  const float* b2  = (const float*)d_in[12];
  const float* g2  = (const float*)d_in[13];
  const float* be2 = (const float*)d_in[14];
  float* ws  = (float*)d_ws;
  float* out = (float*)d_out;

  void* args[] = {(void*)&p,  (void*)&Wc, (void*)&bc,  (void*)&pf,
                  (void*)&Wf, (void*)&bfe,(void*)&W1,  (void*)&b1,
                  (void*)&g1, (void*)&be1,(void*)&W2,  (void*)&b2,
                  (void*)&g2, (void*)&be2,(void*)&ws,  (void*)&out};
  hipLaunchCooperativeKernel((void*)k_all, dim3(256), dim3(512), args, 0, stream);
}

// Round 5
// 612.210 us; speedup vs baseline: 1.0025x; 1.0025x over previous
//
#include <hip/hip_runtime.h>
#include <hip/hip_cooperative_groups.h>

namespace cg = cooperative_groups;

#define BATCH 8
#define PN    16384
#define NSAMP 256
#define KDIM  512
#define HID   384
#define HALF  192
#define CIN   576   // HID + HALF
#define ROWS  2048  // BATCH * NSAMP
#define BN_EPS 1e-5f

// workspace offsets (in floats)
#define OFF_GF   0
#define OFF_W1T  3072
#define OFF_W2T  224256
#define OFF_IDX  371712   /* 2048 ints */
#define OFF_H1   373760
#define OFF_H2   1160192
#define OFF_SUM1 1946624
#define OFF_SQ1  1947008
#define OFF_SUM2 1947392
#define OFF_SQ2  1947776

#define FOREACH32(M) \
  M(0) M(1) M(2) M(3) M(4) M(5) M(6) M(7) \
  M(8) M(9) M(10) M(11) M(12) M(13) M(14) M(15) \
  M(16) M(17) M(18) M(19) M(20) M(21) M(22) M(23) \
  M(24) M(25) M(26) M(27) M(28) M(29) M(30) M(31)

// One cooperative kernel: phase A (FPS blocks 0-7 + prep blocks 8-32),
// grid.sync, gemm1, grid.sync, gemm2, grid.sync, out.
// FPS math is op-for-op identical to the passing R4 kernel; the per-point
// state now lives in NAMED SCALARS (no arrays -> no scratch demotion).
__global__ __launch_bounds__(512) void k_all(
    const float* __restrict__ p,  const float* __restrict__ Wc,
    const float* __restrict__ bc, const float* __restrict__ pf,
    const float* __restrict__ Wf, const float* __restrict__ bfe,
    const float* __restrict__ W1, const float* __restrict__ b1,
    const float* __restrict__ g1, const float* __restrict__ be1,
    const float* __restrict__ W2, const float* __restrict__ b2,
    const float* __restrict__ g2, const float* __restrict__ be2,
    float* __restrict__ ws, float* __restrict__ out) {
  cg::grid_group grid = cg::this_grid();
  int blk = blockIdx.x, t = threadIdx.x;

  __shared__ float s[KDIM];
  __shared__ float Msh[6];
  __shared__ unsigned long long red[2][8];
  __shared__ __align__(16) float ct[CIN * 8];   // phase B staging
  __shared__ __align__(16) float ht[HID * 8];   // phase C staging
  __shared__ float sA[HID], sB[HID];            // BN scale/shift (C, then D)

  int* idx_out = (int*)(ws + OFF_IDX);

  // ======================= Phase A =======================
  if (blk < 8) {
    // ---- FPS, one batch per block (Mahalanobis rank-3 trick) ----
    int b = blk;
    if (t < 64) {                      // G = Wc Wc^T (fp64) + Cholesky, wave 0
      double g0 = 0, g1d = 0, g2d = 0, g3 = 0, g4 = 0, g5 = 0;
      for (int k = t; k < HALF; k += 64) {
        double w0 = (double)Wc[k];
        double w1 = (double)Wc[HALF + k];
        double w2 = (double)Wc[2 * HALF + k];
        g0 += w0 * w0; g1d += w0 * w1; g2d += w0 * w2;
        g3 += w1 * w1; g4  += w1 * w2; g5  += w2 * w2;
      }
      for (int off = 32; off; off >>= 1) {
        g0 += __shfl_down(g0, off, 64); g1d += __shfl_down(g1d, off, 64);
        g2d += __shfl_down(g2d, off, 64); g3 += __shfl_down(g3, off, 64);
        g4 += __shfl_down(g4, off, 64); g5 += __shfl_down(g5, off, 64);
      }
      if (t == 0) {
        double l00 = sqrt(g0);
        double l10 = g1d / l00, l20 = g2d / l00;
        double l11 = sqrt(g3 - l10 * l10);
        double l21 = (g4 - l10 * l20) / l11;
        double l22 = sqrt(g5 - l20 * l20 - l21 * l21);
        Msh[0] = (float)l00; Msh[1] = (float)l10; Msh[2] = (float)l20;
        Msh[3] = (float)l11; Msh[4] = (float)l21; Msh[5] = (float)l22;
      }
    }
    __syncthreads();
    float m00 = Msh[0], m10 = Msh[1], m20 = Msh[2];
    float m11 = Msh[3], m21 = Msh[4], m22 = Msh[5];

    const float* pb = p + b * PN * 3;

    // per-point state in named scalars: qx0..qx31, qy*, qz*, d*
#define DECLP(J) float qx##J, qy##J, qz##J, d##J;
    FOREACH32(DECLP)
#undef DECLP
#define INITP(J) { int i = ((J) << 9) + t;   /* global idx = J*512 + t */   \
    float x = pb[i * 3], y = pb[i * 3 + 1], z = pb[i * 3 + 2];              \
    qx##J = fmaf(m00, x, fmaf(m10, y, m20 * z));                            \
    qy##J = fmaf(m11, y, m21 * z);                                          \
    qz##J = m22 * z;                                                        \
    d##J = 1e10f; }
    FOREACH32(INITP)
#undef INITP

    int far = 0, par = 0;
    for (int k = 0; k < NSAMP; k++) {
      if (t == 0) idx_out[b * NSAMP + k] = far;  // scan emits pre-update far
      float x = pb[far * 3], y = pb[far * 3 + 1], z = pb[far * 3 + 2];
      float cx = fmaf(m00, x, fmaf(m10, y, m20 * z));
      float cy = fmaf(m11, y, m21 * z);
      float cz = m22 * z;
      float bv = -1.f; unsigned bj = 0;
#define UPDP(J) {                                                            \
      float dx = qx##J - cx, dy = qy##J - cy, dz = qz##J - cz;               \
      float dd = fmaf(dx, dx, fmaf(dy, dy, dz * dz));                        \
      float nd = fminf(d##J, dd);                                            \
      d##J = nd;                                                             \
      bool gt = nd > bv;                 /* strict > : first-index tiebreak */\
      bv = gt ? nd : bv;                                                     \
      bj = gt ? (unsigned)(J) : bj; }
      FOREACH32(UPDP)
#undef UPDP
      unsigned bi = (bj << 9) + (unsigned)t;
      // pack: larger dist wins; equal dist -> smaller global index wins (~bi)
      unsigned long long key =
          (((unsigned long long)__float_as_uint(bv)) << 32) | (unsigned)(~bi);
#pragma unroll
      for (int off = 32; off; off >>= 1) {       // per-wave butterfly
        unsigned long long o = __shfl_xor(key, off, 64);
        key = (o > key) ? o : key;
      }
      if ((t & 63) == 0) red[par][t >> 6] = key;
      __syncthreads();                           // the ONLY barrier per step
      // all lanes: read one of 8 slots, 3-level butterfly -> global max
      unsigned long long k2 = red[par][t & 7];
#pragma unroll
      for (int off = 1; off < 8; off <<= 1) {    // (L^off)&7 == (L&7)^off
        unsigned long long o = __shfl_xor(k2, off, 64);
        k2 = (o > k2) ? o : k2;
      }
      far = __builtin_amdgcn_readfirstlane((int)(~((unsigned)k2)));
      par ^= 1;                                  // double-buffer: no 2nd barrier
    }
  } else if (blk < 16) {               // W1t[c][o] = W1[o][c]
    for (int sI = (blk - 8) * 512 + t; sI < HID * CIN; sI += 4096) {
      int o = sI / CIN, c = sI % CIN;
      ws[OFF_W1T + c * HID + o] = W1[sI];
    }
  } else if (blk < 24) {               // W2t[c][o] = W2[o][c]
    for (int sI = (blk - 16) * 512 + t; sI < HID * HID; sI += 4096) {
      int o = sI / HID, c = sI % HID;
      ws[OFF_W2T + c * HID + o] = W2[sI];
    }
  } else if (blk < 32) {               // global_feat[b] = pf[b] @ W_feat + b_feat
    int b = blk - 24;
    s[t] = pf[b * KDIM + t];           // KDIM == 512 == blockDim
    __syncthreads();
    if (t < HID) {
      float acc = bfe[t];
      for (int k = 0; k < KDIM; k++) acc = fmaf(s[k], Wf[k * HID + t], acc);
      ws[OFF_GF + b * HID + t] = acc;
    }
  } else if (blk == 32) {              // zero BN sums (contiguous 1536 floats)
    for (int i = t; i < 1536; i += 512) ws[OFF_SUM1 + i] = 0.f;
  }
  grid.sync();

  // ======================= Phase B: GEMM1 + BN1 sums =======================
  {
    int row0 = blk * 8;
    const int* fidx = (const int*)(ws + OFF_IDX);
    for (int sI = t; sI < 8 * CIN; sI += 512) { // stage tile transposed ct[c*8+r]
      int r = sI / CIN, c = sI % CIN;
      int row = row0 + r, b = row >> 8;
      float val;
      if (c < HID) {
        val = ws[OFF_GF + b * HID + c];          // broadcast global_feat
      } else {
        int co = c - HID;
        int i = fidx[row];
        const float* pp = p + (b * PN + i) * 3;
        val = bc[co];
        val = fmaf(pp[0], Wc[co], val);
        val = fmaf(pp[1], Wc[HALF + co], val);
        val = fmaf(pp[2], Wc[2 * HALF + co], val);  // sampled local_feat
      }
      ct[c * 8 + r] = val;
    }
    __syncthreads();
    if (t < HID) {
      const float* w1t = ws + OFF_W1T;
      float acc[8] = {0.f, 0.f, 0.f, 0.f, 0.f, 0.f, 0.f, 0.f};
      for (int c = 0; c < CIN; c++) {
        float w = w1t[c * HID + t];
        float4 a0 = *(const float4*)(ct + c * 8);
        float4 a1 = *(const float4*)(ct + c * 8 + 4);
        acc[0] = fmaf(a0.x, w, acc[0]); acc[1] = fmaf(a0.y, w, acc[1]);
        acc[2] = fmaf(a0.z, w, acc[2]); acc[3] = fmaf(a0.w, w, acc[3]);
        acc[4] = fmaf(a1.x, w, acc[4]); acc[5] = fmaf(a1.y, w, acc[5]);
        acc[6] = fmaf(a1.z, w, acc[6]); acc[7] = fmaf(a1.w, w, acc[7]);
      }
      float bias = b1[t];
      float sv = 0.f, sq = 0.f;
#pragma unroll
      for (int r = 0; r < 8; r++) {
        float v = acc[r] + bias;
        ws[OFF_H1 + (row0 + r) * HID + t] = v;
        sv += v; sq = fmaf(v, v, sq);
      }
      atomicAdd(&ws[OFF_SUM1 + t], sv);
      atomicAdd(&ws[OFF_SQ1 + t], sq);
    }
  }
  grid.sync();

  // ============== Phase C: GEMM2, BN1 finalize + ReLU fused on load =========
  {
    int row0 = blk * 8;
    if (t < HID) {                     // BN1 finalize, redundantly per block
      float m = ws[OFF_SUM1 + t] * (1.f / ROWS);
      float v = ws[OFF_SQ1 + t] * (1.f / ROWS) - m * m;
      float sc = (1.f / sqrtf(v + BN_EPS)) * g1[t];
      sA[t] = sc;
      sB[t] = be1[t] - m * sc;
    }
    __syncthreads();
    for (int sI = t; sI < 8 * HID; sI += 512) {
      int r = sI / HID, c = sI % HID;
      float x = fmaf(ws[OFF_H1 + (row0 + r) * HID + c], sA[c], sB[c]);
      ht[c * 8 + r] = fmaxf(x, 0.f);
    }
    __syncthreads();
    if (t < HID) {
      const float* w2t = ws + OFF_W2T;
      float acc[8] = {0.f, 0.f, 0.f, 0.f, 0.f, 0.f, 0.f, 0.f};
      for (int c = 0; c < HID; c++) {
        float w = w2t[c * HID + t];
        float4 a0 = *(const float4*)(ht + c * 8);
        float4 a1 = *(const float4*)(ht + c * 8 + 4);
        acc[0] = fmaf(a0.x, w, acc[0]); acc[1] = fmaf(a0.y, w, acc[1]);
        acc[2] = fmaf(a0.z, w, acc[2]); acc[3] = fmaf(a0.w, w, acc[3]);
        acc[4] = fmaf(a1.x, w, acc[4]); acc[5] = fmaf(a1.y, w, acc[5]);
        acc[6] = fmaf(a1.z, w, acc[6]); acc[7] = fmaf(a1.w, w, acc[7]);
      }
      float bias = b2[t];
      float sv = 0.f, sq = 0.f;
#pragma unroll
      for (int r = 0; r < 8; r++) {
        float v = acc[r] + bias;
        ws[OFF_H2 + (row0 + r) * HID + t] = v;
        sv += v; sq = fmaf(v, v, sq);
      }
      atomicAdd(&ws[OFF_SUM2 + t], sv);
      atomicAdd(&ws[OFF_SQ2 + t], sq);
    }
  }
  grid.sync();

  // ============== Phase D: BN2 finalize + affine + ReLU ====================
  {
    if (t < HID) {
      float m = ws[OFF_SUM2 + t] * (1.f / ROWS);
      float v = ws[OFF_SQ2 + t] * (1.f / ROWS) - m * m;
      float sc = (1.f / sqrtf(v + BN_EPS)) * g2[t];
      sA[t] = sc;
      sB[t] = be2[t] - m * sc;
    }
    __syncthreads();
    for (int i4 = blk * 512 + t; i4 < ROWS * HID / 4; i4 += 256 * 512) {
      int i = i4 * 4;
      int c = i % HID;                 // multiple of 4
      float4 h = *(const float4*)(ws + OFF_H2 + i);
      float4 r;
      r.x = fmaxf(fmaf(h.x, sA[c],     sB[c]),     0.f);
      r.y = fmaxf(fmaf(h.y, sA[c + 1], sB[c + 1]), 0.f);
      r.z = fmaxf(fmaf(h.z, sA[c + 2], sB[c + 2]), 0.f);
      r.w = fmaxf(fmaf(h.w, sA[c + 3], sB[c + 3]), 0.f);
      ((float4*)out)[i4] = r;
    }
  }
}

extern "C" void kernel_launch(void* const* d_in, const int* in_sizes, int n_in,
                              void* d_out, int out_size, void* d_ws, size_t ws_size,
                              hipStream_t stream) {
  const float* p   = (const float*)d_in[0];
  // d_in[1] = N (int scalar, always 256)
  const float* pf  = (const float*)d_in[2];
  const float* Wf  = (const float*)d_in[3];
  const float* bfe = (const float*)d_in[4];
  const float* Wc  = (const float*)d_in[5];
  const float* bc  = (const float*)d_in[6];
  const float* W1  = (const float*)d_in[7];
  const float* b1  = (const float*)d_in[8];
  const float* g1  = (const float*)d_in[9];
  const float* be1 = (const float*)d_in[10];
  const float* W2  = (const float*)d_in[11];
  const float* b2  = (const float*)d_in[12];
  const float* g2  = (const float*)d_in[13];
  const float* be2 = (const float*)d_in[14];
  float* ws  = (float*)d_ws;
  float* out = (float*)d_out;

  void* args[] = {(void*)&p,  (void*)&Wc, (void*)&bc,  (void*)&pf,
                  (void*)&Wf, (void*)&bfe,(void*)&W1,  (void*)&b1,
                  (void*)&g1, (void*)&be1,(void*)&W2,  (void*)&b2,
                  (void*)&g2, (void*)&be2,(void*)&ws,  (void*)&out};
  hipLaunchCooperativeKernel((void*)k_all, dim3(256), dim3(512), args, 0, stream);
}